// Round 13
// baseline (959.830 us; speedup 1.0000x reference)
//
#include <hip/hip_runtime.h>
#include <hip/hip_cooperative_groups.h>

namespace cg = cooperative_groups;

#define NN 50000
#define NE 1600000
#define NFEAT 512
#define NHID 64
#define H1 8
#define NCLASS 16
#define ALPHA 0.2f
#define SCAN_BLKS 196
#define COOP_BLKS 1024

typedef __attribute__((ext_vector_type(8))) short short8;
typedef __attribute__((ext_vector_type(4))) float floatx4;
typedef __attribute__((ext_vector_type(2))) float floatx2;

__device__ __forceinline__ float elu_f(float x) { return x > 0.0f ? x : expf(x) - 1.0f; }
__device__ __forceinline__ float edge_w(float logit) {
    return expf(-fmaxf(logit, ALPHA * logit));   // exp(-leaky_relu)
}
__device__ __forceinline__ ushort f2bf(float f) {
    uint u = __float_as_uint(f);
    return (ushort)((u + 0x7FFFu + ((u >> 16) & 1)) >> 16);   // RNE
}
__device__ __forceinline__ uint packbf2(float lo, float hi) {
    return (uint)f2bf(lo) | ((uint)f2bf(hi) << 16);
}
__device__ __forceinline__ float bf2f(ushort v) { return __uint_as_float((uint)v << 16); }
__device__ __forceinline__ unsigned char f2fp8(float v) {
    return (unsigned char)(__builtin_amdgcn_cvt_pk_fp8_f32(v, v, 0, false) & 0xFF);
}
__device__ __forceinline__ uint pack4fp8(float a, float b, float c, float d) {
    uint u = __builtin_amdgcn_cvt_pk_fp8_f32(a, b, 0, false);
    return __builtin_amdgcn_cvt_pk_fp8_f32(c, d, u, true);
}

// ===== cooperative: zero | pack W1 fp8 | pack W2^T bf16 | hist | scan | scatter =====
__global__ void csr_coop_k(const int* __restrict__ ei,
                           const float* __restrict__ W1,
                           unsigned char* __restrict__ Wt8,
                           const float* __restrict__ W2,
                           ushort* __restrict__ W2tb,
                           int* __restrict__ deg,      // [0,NN) deg, [NN,2NN) cursor
                           int* __restrict__ rowptr,
                           int* __restrict__ bsum,
                           ushort* __restrict__ csru) {
    cg::grid_group grid = cg::this_grid();
    const int t = threadIdx.x;
    const int gtid = blockIdx.x * 256 + t;          // 0..262143
    __shared__ int ws[4];

    // phase 0: zero deg+cursor; pack weights (gtid spans exactly 512*512)
    if (gtid < 2 * NN) deg[gtid] = 0;
    {
        int c = gtid >> 9, k = gtid & 511;
        Wt8[gtid] = f2fp8(W1[((c >> 6) * 512 + k) * 64 + (c & 63)]);
    }
    if (gtid < 512 * 16) {
        int c = gtid >> 9, f = gtid & 511;
        W2tb[gtid] = f2bf(W2[f * 16 + c]);
    }
    grid.sync();

    // phase 1: degree histogram
    for (int e = gtid; e < NE; e += COOP_BLKS * 256)
        atomicAdd(&deg[ei[e]], 1);
    grid.sync();

    // phase 2: per-256-chunk exclusive scan
    if (blockIdx.x < SCAN_BLKS) {
        const int lane = t & 63, wv = t >> 6;
        int i = blockIdx.x * 256 + t;
        int v = (i < NN) ? deg[i] : 0;
        int s = v;
#pragma unroll
        for (int o = 1; o < 64; o <<= 1) {
            int u = __shfl_up(s, o);
            if (lane >= o) s += u;
        }
        if (lane == 63) ws[wv] = s;
        __syncthreads();
        if (t == 0) { ws[1] += ws[0]; ws[2] += ws[1]; ws[3] += ws[2]; }
        __syncthreads();
        int excl = s - v + (wv > 0 ? ws[wv - 1] : 0);
        if (i < NN) rowptr[i] = excl;
        if (t == 255) bsum[blockIdx.x] = ws[3];
    }
    grid.sync();

    // phase 3: add block-prefix offsets
    if (blockIdx.x < SCAN_BLKS) {
        const int lane = t & 63, wv = t >> 6;
        __syncthreads();
        int v = (t < SCAN_BLKS && t < (int)blockIdx.x) ? bsum[t] : 0;
#pragma unroll
        for (int o = 1; o < 64; o <<= 1) v += __shfl_xor(v, o);
        if (lane == 0) ws[wv] = v;
        __syncthreads();
        int tot = ws[0] + ws[1] + ws[2] + ws[3];
        int i = blockIdx.x * 256 + t;
        if (i < NN) rowptr[i] += tot;
        if (i == 0) rowptr[NN] = NE;
    }
    grid.sync();

    // phase 4: scatter (cursor = deg + NN)
    for (int e = gtid; e < NE; e += COOP_BLKS * 256) {
        int src = ei[e];
        int pos = rowptr[src] + atomicAdd(&deg[NN + src], 1);
        csru[pos] = (ushort)ei[NE + e];
    }
}

// ===== GEMM1 (fp8 MFMA) 128x128 tile, reads fp32 x directly; scores [n][h] =====
__global__ __launch_bounds__(256) void gemm1_k(const float* __restrict__ x,
                                               const unsigned char* __restrict__ Wt8,
                                               const float* __restrict__ a1,
                                               unsigned char* __restrict__ h8,
                                               float* __restrict__ s1s,
                                               float* __restrict__ s1d) {
    __shared__ unsigned char As[128 * 32];   // [m][k] 4 KB
    __shared__ unsigned char Bs[128 * 32];   // [c][k] 4 KB
    const int tid = threadIdx.x;
    const int wv = tid >> 6, lane = tid & 63;
    const int quad = lane >> 4, l16 = lane & 15;
    const int row0 = blockIdx.y * 128;
    const int col0 = blockIdx.x * 128;
    const int sm = tid >> 2, sk = (tid & 3) * 8;   // 8 fp8 per thread per half
    floatx4 acc[2][8];
#pragma unroll
    for (int rt = 0; rt < 2; rt++)
#pragma unroll
        for (int ct = 0; ct < 8; ct++) acc[rt][ct] = (floatx4){0.f, 0.f, 0.f, 0.f};

    for (int k0 = 0; k0 < 512; k0 += 32) {
#pragma unroll
        for (int p = 0; p < 2; p++) {
            int r = row0 + sm + p * 64;
            float4 f0 = {}, f1 = {};
            if (r < NN) {
                const float* xp = x + (size_t)r * 512 + k0 + sk;
                f0 = *(const float4*)xp;
                f1 = *(const float4*)(xp + 4);
            }
            uint2 av;
            av.x = pack4fp8(f0.x, f0.y, f0.z, f0.w);
            av.y = pack4fp8(f1.x, f1.y, f1.z, f1.w);
            *(uint2*)(As + (sm + p * 64) * 32 + sk) = av;
            int c = col0 + sm + p * 64;
            uint2 bv = *(const uint2*)(Wt8 + (size_t)c * 512 + k0 + sk);
            *(uint2*)(Bs + (sm + p * 64) * 32 + sk) = bv;
        }
        __syncthreads();
        long a0 = *(const long*)(As + (wv * 32 + l16) * 32 + quad * 8);
        long a1f = *(const long*)(As + (wv * 32 + 16 + l16) * 32 + quad * 8);
#pragma unroll
        for (int ct = 0; ct < 8; ct++) {
            long bf = *(const long*)(Bs + (ct * 16 + l16) * 32 + quad * 8);
            acc[0][ct] = __builtin_amdgcn_mfma_f32_16x16x32_fp8_fp8(a0, bf, acc[0][ct], 0, 0, 0);
            acc[1][ct] = __builtin_amdgcn_mfma_f32_16x16x32_fp8_fp8(a1f, bf, acc[1][ct], 0, 0, 0);
        }
        __syncthreads();
    }

#pragma unroll
    for (int rt = 0; rt < 2; rt++) {
        const int rbase = row0 + wv * 32 + rt * 16 + quad * 4;
        float ss[2][4] = {}, sd[2][4] = {};
#pragma unroll
        for (int ct = 0; ct < 8; ct++) {
            int colg = col0 + ct * 16 + l16;
            int head = colg >> 6;
            int hh = ct >> 2;
            float avs = a1[head * 128 + (colg & 63)];
            float avd = a1[head * 128 + 64 + (colg & 63)];
#pragma unroll
            for (int r = 0; r < 4; r++) {
                float v = acc[rt][ct][r];
                ss[hh][r] += v * avs;
                sd[hh][r] += v * avd;
                int row = rbase + r;
                if (row < NN) h8[(size_t)row * 512 + colg] = f2fp8(v);
            }
        }
#pragma unroll
        for (int hh = 0; hh < 2; hh++)
#pragma unroll
            for (int r = 0; r < 4; r++) {
                float a_ = ss[hh][r], b_ = sd[hh][r];
#pragma unroll
                for (int o = 1; o < 16; o <<= 1) {
                    a_ += __shfl_xor(a_, o);
                    b_ += __shfl_xor(b_, o);
                }
                int row = rbase + r;
                if (l16 == 0 && row < NN) {
                    int head = (col0 >> 6) + hh;
                    s1s[row * 8 + head] = a_;    // [node][head]
                    s1d[row * 8 + head] = b_;
                }
            }
    }
}

// ===== fused layer-1 aggregation (fp8 gather) + GEMM2 + layer-2 scores =====
__global__ __launch_bounds__(256) void agg1f_k(const int* __restrict__ rowptr,
                                               const ushort* __restrict__ csru,
                                               const float* __restrict__ s1s,
                                               const float* __restrict__ s1d,
                                               const uint2* __restrict__ hb8,
                                               const ushort* __restrict__ W2tb,
                                               const float* __restrict__ a2,
                                               ushort* __restrict__ h2b,
                                               float* __restrict__ s2s,
                                               float* __restrict__ s2d) {
    __shared__ ushort Ash[16 * 512];
    const int tid = threadIdx.x;
    const int wv = tid >> 6, lane = tid & 63;
    const int n0 = blockIdx.x * 4;
    const int n = n0 + wv;              // NN % 4 == 0
    const int head8 = lane >> 3;
    const int esub = lane & 7;
    const int beg = rowptr[n];
    const int deg = rowptr[n + 1] - beg;
    const float ssrc = s1s[n * 8 + head8];
    floatx2 acc[4] = {};
    float rsum = 0.f;

    int k = 0;
    for (; k + 8 <= deg; k += 8) {
        int dA = csru[beg + k + esub];
        float wA = edge_w(ssrc + s1d[dA * 8 + head8]);
        rsum += wA;
        int dj[8];
#pragma unroll
        for (int j = 0; j < 8; j++) dj[j] = __shfl(dA, j);
        uint2 v[8];
#pragma unroll
        for (int j = 0; j < 8; j++) v[j] = hb8[(uint)dj[j] * 64 + lane];
#pragma unroll
        for (int j = 0; j < 8; j++) {
            float wj = __shfl(wA, (head8 << 3) + j);
            floatx2 w2 = (floatx2){wj, wj};
            acc[0] += w2 * __builtin_amdgcn_cvt_pk_f32_fp8(v[j].x, false);
            acc[1] += w2 * __builtin_amdgcn_cvt_pk_f32_fp8(v[j].x, true);
            acc[2] += w2 * __builtin_amdgcn_cvt_pk_f32_fp8(v[j].y, false);
            acc[3] += w2 * __builtin_amdgcn_cvt_pk_f32_fp8(v[j].y, true);
        }
    }
    if (k < deg) {                       // rem in [1,7]
        int jc = min(k + esub, deg - 1);
        int dwj = csru[beg + jc];
        float w = edge_w(ssrc + s1d[dwj * 8 + head8]);
        if (k + esub >= deg) w = 0.f;
        rsum += w;
        int rem = deg - k;
        for (int j = 0; j < rem; j++) {
            int djs = __shfl(dwj, j);
            uint2 vv = hb8[(uint)djs * 64 + lane];
            float wj = __shfl(w, (head8 << 3) + j);
            floatx2 w2 = (floatx2){wj, wj};
            acc[0] += w2 * __builtin_amdgcn_cvt_pk_f32_fp8(vv.x, false);
            acc[1] += w2 * __builtin_amdgcn_cvt_pk_f32_fp8(vv.x, true);
            acc[2] += w2 * __builtin_amdgcn_cvt_pk_f32_fp8(vv.y, false);
            acc[3] += w2 * __builtin_amdgcn_cvt_pk_f32_fp8(vv.y, true);
        }
    }

    rsum += __shfl_xor(rsum, 1);
    rsum += __shfl_xor(rsum, 2);
    rsum += __shfl_xor(rsum, 4);
    float inv = 1.0f / rsum;
    uint4 o;
    o.x = packbf2(elu_f(acc[0][0] * inv), elu_f(acc[0][1] * inv));
    o.y = packbf2(elu_f(acc[1][0] * inv), elu_f(acc[1][1] * inv));
    o.z = packbf2(elu_f(acc[2][0] * inv), elu_f(acc[2][1] * inv));
    o.w = packbf2(elu_f(acc[3][0] * inv), elu_f(acc[3][1] * inv));
    *(uint4*)(Ash + wv * 512 + lane * 8) = o;
    __syncthreads();

    if (wv == 0) {
        const int l16 = lane & 15, q = lane >> 4;
        floatx4 c2 = (floatx4){0.f, 0.f, 0.f, 0.f};
#pragma unroll
        for (int s = 0; s < 16; s++) {
            short8 af = *(const short8*)(Ash + l16 * 512 + s * 32 + q * 8);
            short8 bf = *(const short8*)(W2tb + l16 * 512 + s * 32 + q * 8);
            c2 = __builtin_amdgcn_mfma_f32_16x16x32_bf16(af, bf, c2, 0, 0, 0);
        }
        if (q == 0) {
#pragma unroll
            for (int r = 0; r < 4; r++) h2b[(size_t)(n0 + r) * 16 + l16] = f2bf(c2[r]);
        }
#pragma unroll
        for (int r = 0; r < 4; r++) {
            float ssv = c2[r] * a2[l16];
            float sdv = c2[r] * a2[16 + l16];
#pragma unroll
            for (int oo = 1; oo < 16; oo <<= 1) {
                ssv += __shfl_xor(ssv, oo);
                sdv += __shfl_xor(sdv, oo);
            }
            if (lane == 0) { s2s[n0 + r] = ssv; s2d[n0 + r] = sdv; }
        }
    }
}

// ===== layer-2 aggregation (bf16 h2, 4-deep) + fused log_softmax =====
__global__ __launch_bounds__(256) void agg2_k(const int* __restrict__ rowptr,
                                              const ushort* __restrict__ csru,
                                              const float* __restrict__ s2s,
                                              const float* __restrict__ s2d,
                                              const ushort* __restrict__ h2b,
                                              float* __restrict__ out) {
    const int n = (blockIdx.x * 256 + threadIdx.x) >> 6;
    const int lane = threadIdx.x & 63;
    if (n >= NN) return;
    const int beg = rowptr[n], end = rowptr[n + 1];
    const float sn = s2s[n];
    const int sub = lane >> 4, f = lane & 15;
    float acc = 0.f, rsum = 0.f;
    int e = beg + sub;
    for (; e + 12 < end; e += 16) {          // 4 edges in flight per subgroup
        int d0 = csru[e], d1 = csru[e + 4], d2 = csru[e + 8], d3 = csru[e + 12];
        float t0 = s2d[d0], t1 = s2d[d1], t2 = s2d[d2], t3 = s2d[d3];
        float g0 = bf2f(h2b[(uint)d0 * 16 + f]), g1 = bf2f(h2b[(uint)d1 * 16 + f]);
        float g2 = bf2f(h2b[(uint)d2 * 16 + f]), g3 = bf2f(h2b[(uint)d3 * 16 + f]);
        float w0 = edge_w(sn + t0), w1 = edge_w(sn + t1);
        float w2 = edge_w(sn + t2), w3 = edge_w(sn + t3);
        acc += w0 * g0 + w1 * g1 + w2 * g2 + w3 * g3;
        rsum += w0 + w1 + w2 + w3;
    }
    for (; e < end; e += 4) {
        int d0 = csru[e];
        float w0 = edge_w(sn + s2d[d0]);
        acc += w0 * bf2f(h2b[(uint)d0 * 16 + f]);
        rsum += w0;
    }
    acc += __shfl_down(acc, 32);
    acc += __shfl_down(acc, 16);
    rsum += __shfl_down(rsum, 32);
    rsum += __shfl_down(rsum, 16);
    if (lane < 16) {
        float v = elu_f(acc / rsum);
        float m = v;
#pragma unroll
        for (int o = 8; o > 0; o >>= 1) m = fmaxf(m, __shfl_xor(m, o));
        float ex = expf(v - m), s = ex;
#pragma unroll
        for (int o = 8; o > 0; o >>= 1) s += __shfl_xor(s, o);
        out[(size_t)n * 16 + f] = v - (logf(s) + m);
    }
}

extern "C" void kernel_launch(void* const* d_in, const int* in_sizes, int n_in,
                              void* d_out, int out_size, void* d_ws, size_t ws_size,
                              hipStream_t stream) {
    const float* x  = (const float*)d_in[0];
    const int*   ei = (const int*)d_in[1];
    const float* W1 = (const float*)d_in[2];
    const float* a1 = (const float*)d_in[3];
    const float* W2 = (const float*)d_in[4];
    const float* a2 = (const float*)d_in[5];
    float* out = (float*)d_out;

    unsigned char* h8  = (unsigned char*)d_ws;           // 25.6M bytes
    unsigned char* Wt8 = h8 + (size_t)NN * 512;          // 262144 bytes
    ushort* W2tb  = (ushort*)(Wt8 + 512 * 512);          // 8192 ushorts
    float* s1s    = (float*)(W2tb + 8192);               // 400K floats [n][h]
    float* s1d    = s1s + (size_t)NN * H1;               // 400K
    int* deg      = (int*)(s1d + (size_t)NN * H1);       // 2*NN (deg + cursor)
    int* rowptr   = deg + 2 * NN;                        // NN+1
    int* bsum     = rowptr + NN + 1;                     // 196 (+pad)
    ushort* csru  = (ushort*)(bsum + 256);               // 1.6M ushort
    ushort* h2b   = csru + NE;                           // 800K ushort
    float* s2s    = (float*)(h2b + (size_t)NN * 16);     // 50000
    float* s2d    = s2s + NN;                            // 50000

    void* cargs[] = {(void*)&ei, (void*)&W1, (void*)&Wt8, (void*)&W2, (void*)&W2tb,
                     (void*)&deg, (void*)&rowptr, (void*)&bsum, (void*)&csru};
    hipLaunchCooperativeKernel((void*)csr_coop_k, dim3(COOP_BLKS), dim3(256),
                               cargs, 0, stream);

    gemm1_k<<<dim3(4, 391), 256, 0, stream>>>(x, Wt8, a1, h8, s1s, s1d);
    agg1f_k<<<NN / 4, 256, 0, stream>>>(rowptr, csru, s1s, s1d,
                                        (const uint2*)h8, W2tb, a2, h2b, s2s, s2d);
    agg2_k<<<(NN + 3) / 4, 256, 0, stream>>>(rowptr, csru, s2s, s2d, h2b, out);
}

// Round 14
// 541.968 us; speedup vs baseline: 1.7710x; 1.7710x over previous
//
#include <hip/hip_runtime.h>

#define NN 50000
#define NE 1600000
#define NFEAT 512
#define NHID 64
#define H1 8
#define NCLASS 16
#define ALPHA 0.2f

typedef __attribute__((ext_vector_type(8))) short short8;
typedef __attribute__((ext_vector_type(4))) float floatx4;
typedef __attribute__((ext_vector_type(2))) float floatx2;

__device__ __forceinline__ float elu_f(float x) { return x > 0.0f ? x : expf(x) - 1.0f; }
__device__ __forceinline__ float edge_w(float logit) {
    return expf(-fmaxf(logit, ALPHA * logit));   // exp(-leaky_relu)
}
__device__ __forceinline__ ushort f2bf(float f) {
    uint u = __float_as_uint(f);
    return (ushort)((u + 0x7FFFu + ((u >> 16) & 1)) >> 16);   // RNE
}
__device__ __forceinline__ uint packbf2(float lo, float hi) {
    return (uint)f2bf(lo) | ((uint)f2bf(hi) << 16);
}
__device__ __forceinline__ float bf2f(ushort v) { return __uint_as_float((uint)v << 16); }
__device__ __forceinline__ unsigned char f2fp8(float v) {
    return (unsigned char)(__builtin_amdgcn_cvt_pk_fp8_f32(v, v, 0, false) & 0xFF);
}
__device__ __forceinline__ uint pack4fp8(float a, float b, float c, float d) {
    uint u = __builtin_amdgcn_cvt_pk_fp8_f32(a, b, 0, false);
    return __builtin_amdgcn_cvt_pk_fp8_f32(c, d, u, true);
}

// ------- phase 0: pack W1 fp8 | pack W2^T bf16 | degree hist -------
#define PACK_BLKS 1024
#define PACK2_BLKS 32
#define DEG_BLKS  6250
__global__ __launch_bounds__(256) void prep_k(const float* __restrict__ W1,
                                              unsigned char* __restrict__ Wt8,
                                              const float* __restrict__ W2,
                                              ushort* __restrict__ W2tb,
                                              const int* __restrict__ ei,
                                              int* __restrict__ deg) {
    int b = blockIdx.x;
    if (b < PACK_BLKS) {
        int i = b * 256 + threadIdx.x;   // i = c*512 + k
        int c = i >> 9, k = i & 511;
        Wt8[i] = f2fp8(W1[((c >> 6) * 512 + k) * 64 + (c & 63)]);
    } else if (b < PACK_BLKS + PACK2_BLKS) {
        int i = (b - PACK_BLKS) * 256 + threadIdx.x;   // i = c*512 + f
        int c = i >> 9, f = i & 511;
        W2tb[i] = f2bf(W2[f * 16 + c]);
    } else {
        int e = (b - PACK_BLKS - PACK2_BLKS) * 256 + threadIdx.x;
        if (e < NE) atomicAdd(&deg[ei[e]], 1);
    }
}

// ---------------- parallel exclusive scan of deg -> rowptr (2 kernels) ----------------
#define SCAN_BLKS 196
__global__ __launch_bounds__(256) void scanA_k(const int* __restrict__ deg,
                                               int* __restrict__ rowptr,
                                               int* __restrict__ bsum) {
    __shared__ int wsum[4];
    const int t = threadIdx.x, lane = t & 63, wv = t >> 6;
    int i = blockIdx.x * 256 + t;
    int v = (i < NN) ? deg[i] : 0;
    int s = v;
#pragma unroll
    for (int o = 1; o < 64; o <<= 1) {
        int u = __shfl_up(s, o);
        if (lane >= o) s += u;
    }
    if (lane == 63) wsum[wv] = s;
    __syncthreads();
    if (t == 0) { wsum[1] += wsum[0]; wsum[2] += wsum[1]; wsum[3] += wsum[2]; }
    __syncthreads();
    int excl = s - v + (wv > 0 ? wsum[wv - 1] : 0);
    if (i < NN) rowptr[i] = excl;
    if (t == 255) bsum[blockIdx.x] = wsum[3];
}

__global__ __launch_bounds__(256) void scanBC_k(int* __restrict__ rowptr,
                                                const int* __restrict__ bsum) {
    __shared__ int ws[4];
    const int t = threadIdx.x, lane = t & 63, wv = t >> 6;
    int v = (t < SCAN_BLKS && t < (int)blockIdx.x) ? bsum[t] : 0;
#pragma unroll
    for (int o = 1; o < 64; o <<= 1) v += __shfl_xor(v, o);
    if (lane == 0) ws[wv] = v;
    __syncthreads();
    int tot = ws[0] + ws[1] + ws[2] + ws[3];
    int i = blockIdx.x * 256 + t;
    if (i < NN) rowptr[i] += tot;
    if (i == 0) rowptr[NN] = NE;
}

// ===== merged: CSR scatter (blocks 0..6249) | GEMM1 fp8 MFMA (blocks 6250..7813) =====
// Both depend only on rowptr; they overlap (scatter = atomic/mem-bound, gemm1 = MFMA-bound).
#define SCAT_BLKS 6250
__global__ __launch_bounds__(256) void scat_gemm1_k(const int* __restrict__ ei,
                                                    const int* __restrict__ rowptr,
                                                    int* __restrict__ cursor,
                                                    ushort* __restrict__ csru,
                                                    const float* __restrict__ x,
                                                    const unsigned char* __restrict__ Wt8,
                                                    const float* __restrict__ a1,
                                                    unsigned char* __restrict__ h8,
                                                    float* __restrict__ s1s,
                                                    float* __restrict__ s1d) {
    __shared__ unsigned char As[128 * 32];   // [m][k] 4 KB
    __shared__ unsigned char Bs[128 * 32];   // [c][k] 4 KB
    const int tid = threadIdx.x;

    if (blockIdx.x < SCAT_BLKS) {
        int e = blockIdx.x * 256 + tid;
        if (e < NE) {
            int src = ei[e];
            int pos = rowptr[src] + atomicAdd(&cursor[src], 1);
            csru[pos] = (ushort)ei[NE + e];
        }
        return;
    }

    const int gb = blockIdx.x - SCAT_BLKS;
    const int col0 = (gb & 3) * 128;      // col-fastest for L2 reuse of x rows
    const int row0 = (gb >> 2) * 128;
    const int wv = tid >> 6, lane = tid & 63;
    const int quad = lane >> 4, l16 = lane & 15;
    const int sm = tid >> 2, sk = (tid & 3) * 8;   // 8 fp8 per thread per half
    floatx4 acc[2][8];
#pragma unroll
    for (int rt = 0; rt < 2; rt++)
#pragma unroll
        for (int ct = 0; ct < 8; ct++) acc[rt][ct] = (floatx4){0.f, 0.f, 0.f, 0.f};

    for (int k0 = 0; k0 < 512; k0 += 32) {
#pragma unroll
        for (int p = 0; p < 2; p++) {
            int r = row0 + sm + p * 64;
            float4 f0 = {}, f1 = {};
            if (r < NN) {
                const float* xp = x + (size_t)r * 512 + k0 + sk;
                f0 = *(const float4*)xp;
                f1 = *(const float4*)(xp + 4);
            }
            uint2 av;
            av.x = pack4fp8(f0.x, f0.y, f0.z, f0.w);
            av.y = pack4fp8(f1.x, f1.y, f1.z, f1.w);
            *(uint2*)(As + (sm + p * 64) * 32 + sk) = av;
            int c = col0 + sm + p * 64;
            uint2 bv = *(const uint2*)(Wt8 + (size_t)c * 512 + k0 + sk);
            *(uint2*)(Bs + (sm + p * 64) * 32 + sk) = bv;
        }
        __syncthreads();
        long a0 = *(const long*)(As + (wv * 32 + l16) * 32 + quad * 8);
        long a1f = *(const long*)(As + (wv * 32 + 16 + l16) * 32 + quad * 8);
#pragma unroll
        for (int ct = 0; ct < 8; ct++) {
            long bf = *(const long*)(Bs + (ct * 16 + l16) * 32 + quad * 8);
            acc[0][ct] = __builtin_amdgcn_mfma_f32_16x16x32_fp8_fp8(a0, bf, acc[0][ct], 0, 0, 0);
            acc[1][ct] = __builtin_amdgcn_mfma_f32_16x16x32_fp8_fp8(a1f, bf, acc[1][ct], 0, 0, 0);
        }
        __syncthreads();
    }

#pragma unroll
    for (int rt = 0; rt < 2; rt++) {
        const int rbase = row0 + wv * 32 + rt * 16 + quad * 4;
        float ss[2][4] = {}, sd[2][4] = {};
#pragma unroll
        for (int ct = 0; ct < 8; ct++) {
            int colg = col0 + ct * 16 + l16;
            int head = colg >> 6;
            int hh = ct >> 2;
            float avs = a1[head * 128 + (colg & 63)];
            float avd = a1[head * 128 + 64 + (colg & 63)];
#pragma unroll
            for (int r = 0; r < 4; r++) {
                float v = acc[rt][ct][r];
                ss[hh][r] += v * avs;
                sd[hh][r] += v * avd;
                int row = rbase + r;
                if (row < NN) h8[(size_t)row * 512 + colg] = f2fp8(v);
            }
        }
#pragma unroll
        for (int hh = 0; hh < 2; hh++)
#pragma unroll
            for (int r = 0; r < 4; r++) {
                float a_ = ss[hh][r], b_ = sd[hh][r];
#pragma unroll
                for (int o = 1; o < 16; o <<= 1) {
                    a_ += __shfl_xor(a_, o);
                    b_ += __shfl_xor(b_, o);
                }
                int row = rbase + r;
                if (l16 == 0 && row < NN) {
                    int head = (col0 >> 6) + hh;
                    s1s[row * 8 + head] = a_;    // [node][head]
                    s1d[row * 8 + head] = b_;
                }
            }
    }
}

// ===== fused layer-1 aggregation (fp8 gather) + GEMM2 + layer-2 scores =====
__global__ __launch_bounds__(256) void agg1f_k(const int* __restrict__ rowptr,
                                               const ushort* __restrict__ csru,
                                               const float* __restrict__ s1s,
                                               const float* __restrict__ s1d,
                                               const uint2* __restrict__ hb8,
                                               const ushort* __restrict__ W2tb,
                                               const float* __restrict__ a2,
                                               ushort* __restrict__ h2b,
                                               float* __restrict__ s2s,
                                               float* __restrict__ s2d) {
    __shared__ ushort Ash[16 * 512];
    const int tid = threadIdx.x;
    const int wv = tid >> 6, lane = tid & 63;
    const int n0 = blockIdx.x * 4;
    const int n = n0 + wv;              // NN % 4 == 0
    const int head8 = lane >> 3;
    const int esub = lane & 7;
    const int beg = rowptr[n];
    const int deg = rowptr[n + 1] - beg;
    const float ssrc = s1s[n * 8 + head8];
    floatx2 acc[4] = {};
    float rsum = 0.f;

    int k = 0;
    for (; k + 8 <= deg; k += 8) {
        int dA = csru[beg + k + esub];
        float wA = edge_w(ssrc + s1d[dA * 8 + head8]);
        rsum += wA;
        int dj[8];
#pragma unroll
        for (int j = 0; j < 8; j++) dj[j] = __shfl(dA, j);
        uint2 v[8];
#pragma unroll
        for (int j = 0; j < 8; j++) v[j] = hb8[(uint)dj[j] * 64 + lane];
#pragma unroll
        for (int j = 0; j < 8; j++) {
            float wj = __shfl(wA, (head8 << 3) + j);
            floatx2 w2 = (floatx2){wj, wj};
            acc[0] += w2 * __builtin_amdgcn_cvt_pk_f32_fp8(v[j].x, false);
            acc[1] += w2 * __builtin_amdgcn_cvt_pk_f32_fp8(v[j].x, true);
            acc[2] += w2 * __builtin_amdgcn_cvt_pk_f32_fp8(v[j].y, false);
            acc[3] += w2 * __builtin_amdgcn_cvt_pk_f32_fp8(v[j].y, true);
        }
    }
    if (k < deg) {                       // rem in [1,7]
        int jc = min(k + esub, deg - 1);
        int dwj = csru[beg + jc];
        float w = edge_w(ssrc + s1d[dwj * 8 + head8]);
        if (k + esub >= deg) w = 0.f;
        rsum += w;
        int rem = deg - k;
        for (int j = 0; j < rem; j++) {
            int djs = __shfl(dwj, j);
            uint2 vv = hb8[(uint)djs * 64 + lane];
            float wj = __shfl(w, (head8 << 3) + j);
            floatx2 w2 = (floatx2){wj, wj};
            acc[0] += w2 * __builtin_amdgcn_cvt_pk_f32_fp8(vv.x, false);
            acc[1] += w2 * __builtin_amdgcn_cvt_pk_f32_fp8(vv.x, true);
            acc[2] += w2 * __builtin_amdgcn_cvt_pk_f32_fp8(vv.y, false);
            acc[3] += w2 * __builtin_amdgcn_cvt_pk_f32_fp8(vv.y, true);
        }
    }

    rsum += __shfl_xor(rsum, 1);
    rsum += __shfl_xor(rsum, 2);
    rsum += __shfl_xor(rsum, 4);
    float inv = 1.0f / rsum;
    uint4 o;
    o.x = packbf2(elu_f(acc[0][0] * inv), elu_f(acc[0][1] * inv));
    o.y = packbf2(elu_f(acc[1][0] * inv), elu_f(acc[1][1] * inv));
    o.z = packbf2(elu_f(acc[2][0] * inv), elu_f(acc[2][1] * inv));
    o.w = packbf2(elu_f(acc[3][0] * inv), elu_f(acc[3][1] * inv));
    *(uint4*)(Ash + wv * 512 + lane * 8) = o;
    __syncthreads();

    if (wv == 0) {
        const int l16 = lane & 15, q = lane >> 4;
        floatx4 c2 = (floatx4){0.f, 0.f, 0.f, 0.f};
#pragma unroll
        for (int s = 0; s < 16; s++) {
            short8 af = *(const short8*)(Ash + l16 * 512 + s * 32 + q * 8);
            short8 bf = *(const short8*)(W2tb + l16 * 512 + s * 32 + q * 8);
            c2 = __builtin_amdgcn_mfma_f32_16x16x32_bf16(af, bf, c2, 0, 0, 0);
        }
        if (q == 0) {
#pragma unroll
            for (int r = 0; r < 4; r++) h2b[(size_t)(n0 + r) * 16 + l16] = f2bf(c2[r]);
        }
#pragma unroll
        for (int r = 0; r < 4; r++) {
            float ssv = c2[r] * a2[l16];
            float sdv = c2[r] * a2[16 + l16];
#pragma unroll
            for (int oo = 1; oo < 16; oo <<= 1) {
                ssv += __shfl_xor(ssv, oo);
                sdv += __shfl_xor(sdv, oo);
            }
            if (lane == 0) { s2s[n0 + r] = ssv; s2d[n0 + r] = sdv; }
        }
    }
}

// ===== layer-2 aggregation (bf16 h2, 4-deep) + fused log_softmax =====
__global__ __launch_bounds__(256) void agg2_k(const int* __restrict__ rowptr,
                                              const ushort* __restrict__ csru,
                                              const float* __restrict__ s2s,
                                              const float* __restrict__ s2d,
                                              const ushort* __restrict__ h2b,
                                              float* __restrict__ out) {
    const int n = (blockIdx.x * 256 + threadIdx.x) >> 6;
    const int lane = threadIdx.x & 63;
    if (n >= NN) return;
    const int beg = rowptr[n], end = rowptr[n + 1];
    const float sn = s2s[n];
    const int sub = lane >> 4, f = lane & 15;
    float acc = 0.f, rsum = 0.f;
    int e = beg + sub;
    for (; e + 12 < end; e += 16) {          // 4 edges in flight per subgroup
        int d0 = csru[e], d1 = csru[e + 4], d2 = csru[e + 8], d3 = csru[e + 12];
        float t0 = s2d[d0], t1 = s2d[d1], t2 = s2d[d2], t3 = s2d[d3];
        float g0 = bf2f(h2b[(uint)d0 * 16 + f]), g1 = bf2f(h2b[(uint)d1 * 16 + f]);
        float g2 = bf2f(h2b[(uint)d2 * 16 + f]), g3 = bf2f(h2b[(uint)d3 * 16 + f]);
        float w0 = edge_w(sn + t0), w1 = edge_w(sn + t1);
        float w2 = edge_w(sn + t2), w3 = edge_w(sn + t3);
        acc += w0 * g0 + w1 * g1 + w2 * g2 + w3 * g3;
        rsum += w0 + w1 + w2 + w3;
    }
    for (; e < end; e += 4) {
        int d0 = csru[e];
        float w0 = edge_w(sn + s2d[d0]);
        acc += w0 * bf2f(h2b[(uint)d0 * 16 + f]);
        rsum += w0;
    }
    acc += __shfl_down(acc, 32);
    acc += __shfl_down(acc, 16);
    rsum += __shfl_down(rsum, 32);
    rsum += __shfl_down(rsum, 16);
    if (lane < 16) {
        float v = elu_f(acc / rsum);
        float m = v;
#pragma unroll
        for (int o = 8; o > 0; o >>= 1) m = fmaxf(m, __shfl_xor(m, o));
        float ex = expf(v - m), s = ex;
#pragma unroll
        for (int o = 8; o > 0; o >>= 1) s += __shfl_xor(s, o);
        out[(size_t)n * 16 + f] = v - (logf(s) + m);
    }
}

extern "C" void kernel_launch(void* const* d_in, const int* in_sizes, int n_in,
                              void* d_out, int out_size, void* d_ws, size_t ws_size,
                              hipStream_t stream) {
    const float* x  = (const float*)d_in[0];
    const int*   ei = (const int*)d_in[1];
    const float* W1 = (const float*)d_in[2];
    const float* a1 = (const float*)d_in[3];
    const float* W2 = (const float*)d_in[4];
    const float* a2 = (const float*)d_in[5];
    float* out = (float*)d_out;

    unsigned char* h8  = (unsigned char*)d_ws;           // 25.6M bytes
    unsigned char* Wt8 = h8 + (size_t)NN * 512;          // 262144 bytes
    ushort* W2tb  = (ushort*)(Wt8 + 512 * 512);          // 8192 ushorts
    float* s1s    = (float*)(W2tb + 8192);               // 400K floats [n][h]
    float* s1d    = s1s + (size_t)NN * H1;               // 400K
    int* deg      = (int*)(s1d + (size_t)NN * H1);       // 2*NN (deg + cursor)
    int* cursor   = deg + NN;
    int* rowptr   = deg + 2 * NN;                        // NN+1
    int* bsum     = rowptr + NN + 1;                     // 196 (+pad)
    ushort* csru  = (ushort*)(bsum + 256);               // 1.6M ushort
    ushort* h2b   = csru + NE;                           // 800K ushort
    float* s2s    = (float*)(h2b + (size_t)NN * 16);     // 50000
    float* s2d    = s2s + NN;                            // 50000

    hipMemsetAsync(deg, 0, 2 * NN * sizeof(int), stream);  // deg + cursor

    prep_k<<<PACK_BLKS + PACK2_BLKS + DEG_BLKS, 256, 0, stream>>>(W1, Wt8, W2, W2tb, ei, deg);
    scanA_k<<<SCAN_BLKS, 256, 0, stream>>>(deg, rowptr, bsum);
    scanBC_k<<<SCAN_BLKS, 256, 0, stream>>>(rowptr, bsum);
    scat_gemm1_k<<<SCAT_BLKS + 4 * 391, 256, 0, stream>>>(ei, rowptr, cursor, csru,
                                                          x, Wt8, a1, h8, s1s, s1d);
    agg1f_k<<<NN / 4, 256, 0, stream>>>(rowptr, csru, s1s, s1d,
                                        (const uint2*)h8, W2tb, a2, h2b, s2s, s2d);
    agg2_k<<<(NN + 3) / 4, 256, 0, stream>>>(rowptr, csru, s2s, s2d, h2b, out);
}